// Round 7
// baseline (222.234 us; speedup 1.0000x reference)
//
#include <hip/hip_runtime.h>
#include <hip/hip_bf16.h>

#define BF __hip_bfloat16

// B=16, C=64, H=128, W=128, MX=MY=24, HIDDEN=32
// fp32 in/out; intermediates bf16.
//
// Workspace (bf16 units, peak 7364608 <= 7471104 budget):
//   gB1 [0,6144)           k_fwd GEMM1 B-table (dead after k_fwd; S overwrites)
//   gB2 [6144,18432)       k_fwd GEMM2 B-table
//   Sr  [0,589824)         [bo][xy]
//   Si  [589824,1179648)
//   Pr  [1179648,4325376)  [bo][u][24y]
//   Pi  [4325376,7340032)  [bo][u][23y] (y=1..23; y=0 identically 0) aliases X
//   Xr  [6160384,6750208)  [xy][bc]    (dead after k_mix; Pi overwrites)
//   Xi  [6750208,7340032)
//   gTw [7340032,7348224)  [v][64k]   gTa [7348224,7356416) [u][64k]
//   wkB [7356416,7360512)  w1B [7360512,7362560)  w2B [7362560,7364608)
//
// R11 (passed, 211.6): k_fused 50.4 (table-hoist worked). Upstream FROZEN at
// ~161 for 3 rounds across compute rewrites -> block-latency-bound: grids
// fill the GPU once, each stage ~ single-block latency, 5-deep serial chain.
// R12: k_fwd / k_invP / k_fused go 8-wave (512 thr), wave owns a 16-row
// m-tile (was 32): per-wave MFMA chain halves, waves/CU doubles (LDS/block
// unchanged). Frag patterns, LDS layouts, barriers, global layouts identical.
// k_mix / k_tw untouched.

typedef __attribute__((ext_vector_type(8))) short s8b;    // 8 bf16 (4 VGPRs)
typedef __attribute__((ext_vector_type(4))) float f32x4;  // MFMA acc

__device__ __forceinline__ float erf_fast(float x) {
    // Abramowitz-Stegun 7.1.26, |eps| <= 1.5e-7
    float ax = fabsf(x);
    float t  = 1.0f / (1.0f + 0.3275911f * ax);
    float p  = t * (0.254829592f + t * (-0.284496736f + t * (1.421413741f
             + t * (-1.453152027f + t * 1.061405429f))));
    float r  = 1.0f - p * __expf(-ax * ax);
    return copysignf(r, x);
}
__device__ __forceinline__ float geluf(float v) {
    return 0.5f * v * (1.0f + erf_fast(v * 0.7071067811865476f));
}
__device__ __forceinline__ float bf2f(BF v) { return __bfloat162float(v); }
__device__ __forceinline__ short f2bs(float f) {
    union { BF h; short s; } u; u.h = __float2bfloat16(f); return u.s;
}
__device__ __forceinline__ s8b ld8f(const float* __restrict__ p) {
    float4 a = *(const float4*)p;
    float4 b = *(const float4*)(p + 4);
    s8b r;
    r[0] = f2bs(a.x); r[1] = f2bs(a.y); r[2] = f2bs(a.z); r[3] = f2bs(a.w);
    r[4] = f2bs(b.x); r[5] = f2bs(b.y); r[6] = f2bs(b.z); r[7] = f2bs(b.w);
    return r;
}

// ---------------------------------------------------------------------------
// k_tw: all precomputed tables.  43008 elements, grid 168 x 256. (unchanged)
// ---------------------------------------------------------------------------
__global__ __launch_bounds__(256) void k_tw(const float* __restrict__ wsk,
                                            const float* __restrict__ w1,
                                            const float* __restrict__ w2,
                                            BF* __restrict__ gB1,
                                            BF* __restrict__ gB2,
                                            BF* __restrict__ gTw,
                                            BF* __restrict__ gTa,
                                            BF* __restrict__ wkB,
                                            BF* __restrict__ w1B,
                                            BF* __restrict__ w2B) {
    const int idx = blockIdx.x * 256 + threadIdx.x;
    const float th = 0.04908738521234052f;   // 2*pi/128
    if (idx < 6144) {                        // gB1[y'][v]
        int y = idx >> 7, v = idx & 127;
        int yy = (y < 24) ? y : y - 24;
        int r = (v * yy) & 127;
        float s, c; __sincosf((float)r * th, &s, &c);
        gB1[idx] = __float2bfloat16(y < 24 ? c : -s);
    } else if (idx < 18432) {                // gB2[x'][k]
        int j = idx - 6144;
        int xp = j >> 8, k = j & 255;
        int u = k & 127, half = k >> 7;
        int x = (xp < 24) ? xp : xp - 24;
        int r = (u * x) & 127;
        float s, c; __sincosf((float)r * th, &s, &c);
        float val = (xp < 24) ? (half ? s : c) : (half ? c : -s);
        gB2[j] = __float2bfloat16(val);
    } else if (idx < 26624) {                // gTw[v][k]: k<24 cos, 24..47 -sin
        int j = idx - 18432;
        int v = j >> 6, k = j & 63;
        float val = 0.f;
        if (k < 24)      val =  __cosf((float)((v * k) & 127) * th);
        else if (k < 48) val = -__sinf((float)((v * (k - 24)) & 127) * th);
        gTw[j] = __float2bfloat16(val);
    } else if (idx < 34816) {                // gTa[u][k]: k<24 cos, 24..47 +sin
        int j = idx - 26624;
        int u = j >> 6, k = j & 63;
        float val = 0.f;
        if (k < 24)      val = __cosf((float)((u * k) & 127) * th);
        else if (k < 48) val = __sinf((float)((u * (k - 24)) & 127) * th);
        gTa[j] = __float2bfloat16(val);
    } else if (idx < 38912) {                // wkB
        int j = idx - 34816;
        wkB[j] = __float2bfloat16(wsk[j]);
    } else if (idx < 40960) {                // w1B
        int j = idx - 38912;
        w1B[j] = __float2bfloat16(w1[j]);
    } else if (idx < 43008) {                // w2B
        int j = idx - 40960;
        w2B[j] = __float2bfloat16(w2[j]);
    }
}

// ---------------------------------------------------------------------------
// k_fwd (8-wave): both forward DFTs for one bc, on MFMA.
// Wave wv owns u-tile [wv*16, wv*16+16) in GEMM1 (3 n-tiles, 12 MFMA).
// ---------------------------------------------------------------------------
__global__ __launch_bounds__(512) void k_fwd(const float* __restrict__ x,
                                             const BF* __restrict__ gB1,
                                             const BF* __restrict__ gB2,
                                             BF* __restrict__ XrB,
                                             BF* __restrict__ XiB) {
    __shared__ __align__(16) short Tl[48 * 136];

    const int tid  = threadIdx.x;
    const int bc   = blockIdx.x;
    const int lane = tid & 63;
    const int wv   = tid >> 6;     // 0..7
    const int lr   = lane & 15;
    const int lg   = lane >> 4;

    // ---- GEMM1: M=128 (u, wave wv rows wv*16..+16), N=48, K=128.
    {
        const float* xb = x + ((size_t)bc << 14);
        const int u = wv * 16 + lr;
        s8b af[4];
        #pragma unroll
        for (int s = 0; s < 4; ++s)
            af[s] = ld8f(xb + (size_t)u * 128 + s * 32 + lg * 8);
        f32x4 acc[3];
        #pragma unroll
        for (int n = 0; n < 3; ++n)
            #pragma unroll
            for (int r = 0; r < 4; ++r) acc[n][r] = 0.f;
        #pragma unroll
        for (int s = 0; s < 4; ++s)
            #pragma unroll
            for (int n = 0; n < 3; ++n) {
                s8b bfr = *(const s8b*)((const short*)gB1 + (n * 16 + lr) * 128 + s * 32 + lg * 8);
                acc[n] = __builtin_amdgcn_mfma_f32_16x16x32_bf16(af[s], bfr, acc[n], 0, 0, 0);
            }
        const int u0 = wv * 16 + lg * 4;
        #pragma unroll
        for (int n = 0; n < 3; ++n) {
            short4 t;
            t.x = f2bs(acc[n][0]); t.y = f2bs(acc[n][1]);
            t.z = f2bs(acc[n][2]); t.w = f2bs(acc[n][3]);
            *(short4*)&Tl[(n * 16 + lr) * 136 + u0] = t;
        }
    }
    __syncthreads();

    // ---- GEMM2: M=24 (y, pad 32), N=48, K=256.  6 tile-jobs over 8 waves.
    if (wv < 6) {
        const int j = wv;
        const int m = j / 3, n = j % 3;
        const int y  = m * 16 + lr;
        const int r1 = (y < 24) ? y      : 0;
        const int r2 = (y < 24) ? y + 24 : 0;
        f32x4 acc = {0.f, 0.f, 0.f, 0.f};
        #pragma unroll
        for (int s = 0; s < 8; ++s) {
            s8b a = *(const s8b*)&Tl[((s < 4) ? r1 : r2) * 136 + (s & 3) * 32 + lg * 8];
            s8b b = *(const s8b*)((const short*)gB2 + (n * 16 + lr) * 256 + s * 32 + lg * 8);
            acc = __builtin_amdgcn_mfma_f32_16x16x32_bf16(a, b, acc, 0, 0, 0);
        }
        const int col = n * 16 + lr;
        const int xc  = (col < 24) ? col : col - 24;
        BF* dst = (col < 24) ? XrB : XiB;
        #pragma unroll
        for (int r = 0; r < 4; ++r) {
            const int yo = m * 16 + lg * 4 + r;
            if (yo < 24)
                dst[(size_t)(xc * 24 + yo) * 1024 + bc] = __float2bfloat16(acc[r]);
        }
    }
}

// ---------------------------------------------------------------------------
// k_mix (MFMA): per-mode complex channel mix.  Block = xy (576), 256 thr.
// (unchanged from R11)
// ---------------------------------------------------------------------------
__global__ __launch_bounds__(256) void k_mix(const float* __restrict__ wr_g,
                                             const float* __restrict__ wi_g,
                                             const BF* __restrict__ XrB,
                                             const BF* __restrict__ XiB,
                                             BF* __restrict__ SrB,
                                             BF* __restrict__ SiB) {
    __shared__ __align__(16) short Br[64 * 72], Bi[64 * 72];   // [o][c]
    const int tid  = threadIdx.x;
    const int xy   = blockIdx.x;
    const int lane = tid & 63;
    const int wv   = tid >> 6;
    const int lr   = lane & 15;
    const int lg   = lane >> 4;

    const float* wrp = wr_g + ((size_t)xy << 12);
    const float* wip = wi_g + ((size_t)xy << 12);
    for (int i = tid; i < 4096; i += 256) {
        int c = i >> 6, o = i & 63;
        Br[o * 72 + c] = f2bs(wrp[i]);
        Bi[o * 72 + c] = f2bs(wip[i]);
    }

    s8b axr[2], axi[2], axin[2];
    {
        const short* xr = (const short*)XrB + ((size_t)xy << 10) + lr * 64;
        const short* xi = (const short*)XiB + ((size_t)xy << 10) + lr * 64;
        #pragma unroll
        for (int s = 0; s < 2; ++s) {
            axr[s] = *(const s8b*)(xr + s * 32 + lg * 8);
            axi[s] = *(const s8b*)(xi + s * 32 + lg * 8);
            #pragma unroll
            for (int j = 0; j < 8; ++j)
                axin[s][j] = axi[s][j] ^ (short)0x8000;
        }
    }
    __syncthreads();

    f32x4 ar = {0.f, 0.f, 0.f, 0.f}, ai = {0.f, 0.f, 0.f, 0.f};
    #pragma unroll
    for (int s = 0; s < 2; ++s) {
        s8b wrf = *(const s8b*)&Br[(wv * 16 + lr) * 72 + s * 32 + lg * 8];
        s8b wif = *(const s8b*)&Bi[(wv * 16 + lr) * 72 + s * 32 + lg * 8];
        ar = __builtin_amdgcn_mfma_f32_16x16x32_bf16(axr[s],  wrf, ar, 0, 0, 0);
        ar = __builtin_amdgcn_mfma_f32_16x16x32_bf16(axin[s], wif, ar, 0, 0, 0);
        ai = __builtin_amdgcn_mfma_f32_16x16x32_bf16(axr[s],  wif, ai, 0, 0, 0);
        ai = __builtin_amdgcn_mfma_f32_16x16x32_bf16(axi[s],  wrf, ai, 0, 0, 0);
    }

    const int o = wv * 16 + lr;
    #pragma unroll
    for (int r = 0; r < 4; ++r) {
        int b = lg * 4 + r;
        size_t base = (size_t)((b << 6) + o) * 576 + xy;
        SrB[base] = __float2bfloat16(ar[r]);
        SiB[base] = __float2bfloat16(ai[r]);
    }
}

// ---------------------------------------------------------------------------
// k_invP (8-wave): inverse H-transform.  Block = bo (1024), 512 thr.
// Wave wv owns u-tile [wv*16, wv*16+16): 3 n-jobs x 2 MFMA.
// ---------------------------------------------------------------------------
__global__ __launch_bounds__(512) void k_invP(const BF* __restrict__ SrB,
                                              const BF* __restrict__ SiB,
                                              const BF* __restrict__ gTa,
                                              BF* __restrict__ PrB,
                                              BF* __restrict__ PiB) {
    __shared__ __align__(16) short Bp[48 * 72];   // 6.9 KB, write-once
    const int tid  = threadIdx.x;
    const int bo   = blockIdx.x;
    const int lane = tid & 63;
    const int wv   = tid >> 6;     // 0..7
    const int lr   = lane & 15;
    const int lg   = lane >> 4;
    const float inv = 6.103515625e-05f;   // 1/16384

    for (int i = tid; i < 576; i += 512) {
        int x = i / 24, y = i - x * 24;
        float sr = bf2f(SrB[(size_t)bo * 576 + i]);
        float si = bf2f(SiB[(size_t)bo * 576 + i]);
        float sc = (y == 0) ? inv : 2.0f * inv;
        Bp[y * 72 + x]             = f2bs(sc * sr);
        Bp[y * 72 + 24 + x]        = f2bs(-sc * si);
        Bp[(24 + y) * 72 + x]      = f2bs((y == 0) ? 0.f : sc * si);
        Bp[(24 + y) * 72 + 24 + x] = f2bs((y == 0) ? 0.f : sc * sr);
    }
    for (int i = tid; i < 768; i += 512)          // zero K-pad [48,64)
        Bp[(i >> 4) * 72 + 48 + (i & 15)] = 0;

    // A twiddle frags from table
    s8b a[2];
    {
        const short* gta = (const short*)gTa;
        const int u = wv * 16 + lr;
        #pragma unroll
        for (int s = 0; s < 2; ++s)
            a[s] = *(const s8b*)&gta[u * 64 + s * 32 + lg * 8];
    }
    __syncthreads();

    #pragma unroll
    for (int n = 0; n < 3; ++n) {
        f32x4 acc = {0.f, 0.f, 0.f, 0.f};
        #pragma unroll
        for (int s = 0; s < 2; ++s) {
            s8b bfr = *(const s8b*)&Bp[(n * 16 + lr) * 72 + s * 32 + lg * 8];
            acc = __builtin_amdgcn_mfma_f32_16x16x32_bf16(a[s], bfr, acc, 0, 0, 0);
        }
        const int col = n * 16 + lr;
        #pragma unroll
        for (int r = 0; r < 4; ++r) {
            const int u = wv * 16 + lg * 4 + r;
            if (col < 24) {
                PrB[(size_t)bo * 3072 + (size_t)u * 24 + col] = __float2bfloat16(acc[r]);
            } else {
                const int y = col - 24;
                if (y > 0)
                    PiB[(size_t)bo * 2944 + (size_t)u * 23 + (y - 1)] = __float2bfloat16(acc[r]);
            }
        }
    }
}

// ---------------------------------------------------------------------------
// k_fused (8-wave, D[o][v], table operands): inverse W-transform + skip +
// GELU + MLP + soft-gate.  Block = (b,u): 2048 blocks, 512 thr.
// Wave wv owns v-cols [wv*16, wv*16+16): 12 MFMA phase1, 4 fc1, 4 fc2.
// ---------------------------------------------------------------------------
__global__ __launch_bounds__(512) void k_fused(const float* __restrict__ x,
                                               const BF* __restrict__ PrB,
                                               const BF* __restrict__ PiB,
                                               const BF* __restrict__ gTw,
                                               const BF* __restrict__ wkB,
                                               const BF* __restrict__ w1B,
                                               const BF* __restrict__ w2B,
                                               const float* __restrict__ b1,
                                               const float* __restrict__ b2,
                                               const float* __restrict__ gt,
                                               float* __restrict__ out) {
    __shared__ __align__(16) short Plds[64 * 72];    // P^T [o][k]
    __shared__ __align__(16) short H1s[128 * 72];    // h1 bf16 [v][o]
    __shared__ __align__(16) short Zls[128 * 40];    // z  bf16 [v][kh]

    const int tid  = threadIdx.x;
    const int b    = blockIdx.x >> 7;
    const int u    = blockIdx.x & 127;
    const int lane = tid & 63;
    const int wv   = tid >> 6;     // 0..7
    const int lr   = lane & 15;
    const int lg   = lane >> 4;
    const int vb   = wv * 16;      // wave v-base
    const int b64  = b * 64;

    // ---- stage P^T: cols 0..23 = Pr y, 24 = 0 (Pi y=0), 25..47 = Pi y=1..23
    for (int i = tid; i < 1536; i += 512) {
        int o = i / 24, y = i - o * 24;
        Plds[o * 72 + y] = *(const short*)&PrB[(size_t)(b64 + o) * 3072 + (size_t)u * 24 + y];
    }
    for (int i = tid; i < 1472; i += 512) {
        int o = i / 23, y1 = i - o * 23;
        Plds[o * 72 + 25 + y1] = *(const short*)&PiB[(size_t)(b64 + o) * 2944 + (size_t)u * 23 + y1];
    }
    if (tid < 64) Plds[tid * 72 + 24] = 0;
    for (int i = tid; i < 1024; i += 512)
        Plds[(i >> 4) * 72 + 48 + (i & 15)] = 0;

    // ---- x B-frags (col v = vb + lr)
    s8b bx[2];
    {
        const float* xb = x + (size_t)b64 * 16384 + (size_t)u * 128;
        const int v = vb + lr;
        #pragma unroll
        for (int s = 0; s < 2; ++s)
            #pragma unroll
            for (int j = 0; j < 8; ++j)
                bx[s][j] = f2bs(xb[(size_t)(s * 32 + lg * 8 + j) * 16384 + v]);
    }

    // ---- twiddle B-frags from table
    s8b btw[2];
    {
        const short* gtw = (const short*)gTw;
        const int v = vb + lr;
        #pragma unroll
        for (int s = 0; s < 2; ++s)
            btw[s] = *(const s8b*)&gtw[v * 64 + s * 32 + lg * 8];
    }
    __syncthreads();   // Plds staged

    const short* wkb = (const short*)wkB;
    const short* w1b = (const short*)w1B;
    const short* w2b = (const short*)w2B;

    // ---- GEMM 1+2: spec + skip, D[o][v]
    f32x4 acc[4];
    #pragma unroll
    for (int mo = 0; mo < 4; ++mo)
        #pragma unroll
        for (int r = 0; r < 4; ++r) acc[mo][r] = 0.f;

    #pragma unroll
    for (int s = 0; s < 2; ++s)
        #pragma unroll
        for (int mo = 0; mo < 4; ++mo) {
            s8b ap = *(const s8b*)&Plds[(mo * 16 + lr) * 72 + s * 32 + lg * 8];
            acc[mo] = __builtin_amdgcn_mfma_f32_16x16x32_bf16(ap, btw[s], acc[mo], 0, 0, 0);
        }
    #pragma unroll
    for (int s = 0; s < 2; ++s)
        #pragma unroll
        for (int mo = 0; mo < 4; ++mo) {
            s8b aw = *(const s8b*)&wkb[(mo * 16 + lr) * 64 + s * 32 + lg * 8];
            acc[mo] = __builtin_amdgcn_mfma_f32_16x16x32_bf16(aw, bx[s], acc[mo], 0, 0, 0);
        }

    // ---- h1 = gelu(acc): element (o = mo*16+lg*4+r, v = vb+lr)
    f32x4 h1r[4];
    #pragma unroll
    for (int mo = 0; mo < 4; ++mo)
        #pragma unroll
        for (int r = 0; r < 4; ++r) {
            float h = geluf(acc[mo][r]);
            h1r[mo][r] = h;
            H1s[(vb + lr) * 72 + mo * 16 + lg * 4 + r] = f2bs(h);
        }
    __syncthreads();   // H1 complete

    // ---- fc1: z^T[kh][v] = gelu(w1 @ h1^T + b1)
    f32x4 zac[2];
    #pragma unroll
    for (int mk = 0; mk < 2; ++mk)
        #pragma unroll
        for (int r = 0; r < 4; ++r) zac[mk][r] = 0.f;
    #pragma unroll
    for (int s = 0; s < 2; ++s) {
        s8b bh = *(const s8b*)&H1s[(vb + lr) * 72 + s * 32 + lg * 8];
        #pragma unroll
        for (int mk = 0; mk < 2; ++mk) {
            s8b aw = *(const s8b*)&w1b[(mk * 16 + lr) * 64 + s * 32 + lg * 8];
            zac[mk] = __builtin_amdgcn_mfma_f32_16x16x32_bf16(aw, bh, zac[mk], 0, 0, 0);
        }
    }
    #pragma unroll
    for (int mk = 0; mk < 2; ++mk)
        #pragma unroll
        for (int r = 0; r < 4; ++r) {
            const float bb = b1[mk * 16 + lg * 4 + r];
            Zls[(vb + lr) * 40 + mk * 16 + lg * 4 + r] = f2bs(geluf(zac[mk][r] + bb));
        }
    __syncthreads();   // Zl complete

    // ---- fc2: out[o][v] = w2 @ z^T + b2 + gate*h1, K=32
    f32x4 oac[4];
    #pragma unroll
    for (int mo = 0; mo < 4; ++mo)
        #pragma unroll
        for (int r = 0; r < 4; ++r) oac[mo][r] = 0.f;
    s8b bz = *(const s8b*)&Zls[(vb + lr) * 40 + lg * 8];
    #pragma unroll
    for (int mo = 0; mo < 4; ++mo) {
        s8b aw = *(const s8b*)&w2b[(mo * 16 + lr) * 32 + lg * 8];
        oac[mo] = __builtin_amdgcn_mfma_f32_16x16x32_bf16(aw, bz, oac[mo], 0, 0, 0);
    }

    // ---- epilogue: v-contiguous stores
    float* ob = out + (size_t)b64 * 16384 + (size_t)u * 128;
    #pragma unroll
    for (int mo = 0; mo < 4; ++mo)
        #pragma unroll
        for (int r = 0; r < 4; ++r) {
            const int o = mo * 16 + lg * 4 + r;
            ob[(size_t)o * 16384 + vb + lr] = oac[mo][r] + b2[o] + gt[o] * h1r[mo][r];
        }
}

// ---------------------------------------------------------------------------
extern "C" void kernel_launch(void* const* d_in, const int* in_sizes, int n_in,
                              void* d_out, int out_size, void* d_ws, size_t ws_size,
                              hipStream_t stream) {
    (void)in_sizes; (void)n_in; (void)out_size; (void)ws_size;
    const float* x   = (const float*)d_in[0];
    const float* wr  = (const float*)d_in[1];
    const float* wi  = (const float*)d_in[2];
    const float* wsk = (const float*)d_in[3];
    const float* w1  = (const float*)d_in[4];
    const float* b1  = (const float*)d_in[5];
    const float* w2  = (const float*)d_in[6];
    const float* b2  = (const float*)d_in[7];
    const float* gt  = (const float*)d_in[8];

    BF* wsB = (BF*)d_ws;
    BF* gB1 = wsB;                 // [0, 6144)        dead after k_fwd
    BF* gB2 = wsB + 6144;          // [6144, 18432)    dead after k_fwd
    BF* Sr  = wsB;                 // [0, 589824)      overwrites gB1/gB2 (legal)
    BF* Si  = wsB + 589824;        // [589824, 1179648)
    BF* Pr  = wsB + 1179648;       // [1179648, 4325376)
    BF* Pi  = wsB + 4325376;       // [4325376, 7340032)  23-plane; aliases X (X dead)
    BF* Xr  = wsB + 6160384;       // [6160384, 6750208)  dead after k_mix
    BF* Xi  = wsB + 6750208;       // [6750208, 7340032)
    BF* gTw = wsB + 7340032;       // [7340032, 7348224)  live whole run
    BF* gTa = wsB + 7348224;       // [7348224, 7356416)
    BF* wkB = wsB + 7356416;       // [7356416, 7360512)
    BF* w1B = wsB + 7360512;       // [7360512, 7362560)
    BF* w2B = wsB + 7362560;       // [7362560, 7364608)
    // peak footprint: 7364608 bf16 = 14.73 MB

    hipLaunchKernelGGL(k_tw,   dim3(168),  dim3(256), 0, stream,
                       wsk, w1, w2, gB1, gB2, gTw, gTa, wkB, w1B, w2B);
    hipLaunchKernelGGL(k_fwd,  dim3(1024), dim3(512), 0, stream, x, gB1, gB2, Xr, Xi);
    hipLaunchKernelGGL(k_mix,  dim3(576),  dim3(256), 0, stream, wr, wi, Xr, Xi, Sr, Si);
    hipLaunchKernelGGL(k_invP, dim3(1024), dim3(512), 0, stream, Sr, Si, gTa, Pr, Pi);
    hipLaunchKernelGGL(k_fused, dim3(2048), dim3(512), 0, stream,
                       x, Pr, Pi, gTw, wkB, w1B, w2B, b1, b2, gt, (float*)d_out);
}